// Round 3
// baseline (92.484 us; speedup 1.0000x reference)
//
#include <hip/hip_runtime.h>
#include <math.h>

#define N    8192
#define DIM  64
#define KSEL 32

// ---------------------------------------------------------------------------
// Kernel A v5: v = tanh(3 * (emb[idx] @ W^T + b))
// Same read-role structure as v4 (W rows in VGPRs, e[] as ds_read_b128
// broadcasts), but 32 rows/block (grid 512):
//   - W staging traffic halves (512 x 16KB = 8MB from L2),
//   - the one-time 8-way-conflict W-register pull amortizes over 8 rows/wave.
// FP accumulation order identical (sequential k=0..63, tanhf(3*acc))
// -> v1/v2 bit-identical to the passing kernel.
// ---------------------------------------------------------------------------
__global__ __launch_bounds__(256) void embed_linear_tanh(
    const int*   __restrict__ idx,
    const float* __restrict__ emb1,
    const float* __restrict__ emb2,
    const float* __restrict__ W,     // [DIM][DIM], out[d] = dot(e, W[d,:]) + b[d]
    const float* __restrict__ b,
    float* __restrict__ v1,
    float* __restrict__ v2)
{
    __shared__ float Wp[DIM][DIM + 4];   // +4 pad: rows stay 16B-aligned (272 B stride)
    __shared__ float e[32][DIM];         // broadcast reads (same addr per wave) -> no pad

    const int t = threadIdx.x;
    const int m = blockIdx.x & 1;                 // 0: emb1->v1, 1: emb2->v2
    const int rowbase = (int)(blockIdx.x >> 1) * 32;
    const float* __restrict__ emb  = m ? emb2 : emb1;
    float*       __restrict__ vout = m ? v2   : v1;

    // stage W (4096 floats) coalesced: 256 threads * 4 float4
    {
        const float4* W4 = (const float4*)W;
        #pragma unroll
        for (int s = 0; s < 4; ++s) {
            int e4 = t + s * 256;          // 0..1023
            float4 wvv = W4[e4];
            int d = e4 >> 4;
            int k = (e4 & 15) * 4;
            *(float4*)&Wp[d][k] = wvv;
        }
    }
    // stage 32 gathered emb rows (2048 floats): thread t -> row t>>3, 2 float4 segs
    {
        int r = t >> 3, s0 = (t & 7) * 2;
        int g = idx[rowbase + r];
        const float4* src = (const float4*)(emb + (size_t)g * DIM);
        float4 x0 = src[s0];
        float4 x1 = src[s0 + 1];
        *(float4*)&e[r][s0 * 4]     = x0;
        *(float4*)&e[r][s0 * 4 + 4] = x1;
    }
    __syncthreads();

    const int l  = t & 63;   // lane = output dim
    const int wv = t >> 6;   // wave index

    // pull W row l into registers (one-time; 8-way LDS conflict acceptable)
    float4 w[16];
    #pragma unroll
    for (int q = 0; q < 16; ++q) w[q] = *(const float4*)&Wp[l][q * 4];
    const float bias = b[l];

    #pragma unroll
    for (int rr = 0; rr < 8; ++rr) {
        const int r = wv + rr * 4;         // same r across a wave -> e[] broadcast
        float acc = bias;
        #pragma unroll
        for (int q = 0; q < 16; ++q) {
            const float4 ev = *(const float4*)&e[r][q * 4];   // broadcast b128
            acc += ev.x * w[q].x;    // sequential fmac chain: identical FP
            acc += ev.y * w[q].y;    // order to the passing kernel
            acc += ev.z * w[q].z;
            acc += ev.w * w[q].w;
        }
        vout[(size_t)(rowbase + r) * DIM + l] = tanhf(3.0f * acc);
    }
}

// ---------------------------------------------------------------------------
// Kernel B v6: round-0 proven structure, but 128-column staging rounds.
// Two 64-col halves are computed per barrier pair -> barrier rounds drop from
// ~3-4 to ~2 (expected max-over-16-rows completion ~ col 200-256).
// LDS 2 x 64KB + colbuf = ~66KB -> still 2 blocks/CU.
// Numerics: identical FP chain and ascending-column ballot order.
// ---------------------------------------------------------------------------
__global__ __launch_bounds__(256, 2) void build_graph(
    const float* __restrict__ v1,
    const float* __restrict__ v2,
    float* __restrict__ out_rows,
    float* __restrict__ out_cols,
    float* __restrict__ out_data)
{
    __shared__ float4 c1v[16][128];  // [k4][col] : lane pull stride 16B -> conflict-free
    __shared__ float4 c2v[16][128];
    __shared__ int    colbuf[16][KSEL];
    __shared__ int    wdone[4];

    const int t = threadIdx.x;
    const int l = t & 63;            // lane
    const int w = __builtin_amdgcn_readfirstlane(t >> 6);   // wave 0..3, forced SGPR
    const int rowbase = (int)blockIdx.x * 16;

    if (l == 0) wdone[w] = 0;
    __syncthreads();

    int  cnt[4] = {0, 0, 0, 0};      // per-row saturated-count (wave-uniform)
    bool done = false;
    const int sr = t >> 1;           // staging: column row 0..127
    const int sq = t & 1;            // staging: which 8-float4 half of the row

    for (int rd = 0; rd < N / 128; ++rd) {
        const int cbase = rd * 128;
        // ---- cooperative staging: 128 column rows of v1,v2 -> LDS ----
        // thread t: row (cbase+sr), f4 segs sq*8..sq*8+7 (128B contiguous);
        // wave covers 32 rows x 256B = 8KB contiguous -> coalesced.
        {
            const float4* p1 = (const float4*)(v1 + (size_t)(cbase + sr) * DIM) + sq * 8;
            const float4* p2 = (const float4*)(v2 + (size_t)(cbase + sr) * DIM) + sq * 8;
            #pragma unroll
            for (int s = 0; s < 8; ++s) {
                c1v[sq * 8 + s][sr] = p1[s];
                c2v[sq * 8 + s][sr] = p2[s];
            }
        }
        __syncthreads();

        if (!done) {
            bool all_done = true;
            #pragma unroll
            for (int h = 0; h < 2; ++h) {            // two 64-col halves, ascending
                // pull column (cbase + h*64 + l) into registers: conflict-free b128
                float4 c1r[16], c2r[16];
                #pragma unroll
                for (int k4 = 0; k4 < 16; ++k4) {
                    c1r[k4] = c1v[k4][h * 64 + l];
                    c2r[k4] = c2v[k4][h * 64 + l];
                }
                #pragma unroll
                for (int rr = 0; rr < 4; ++rr) {
                    if (cnt[rr] < KSEL) {            // wave-uniform branch
                        const int wrow = w * 4 + rr;
                        const int i = rowbase + wrow;                 // uniform
                        const float* __restrict__ r1 = v1 + (size_t)i * DIM;  // -> s_load
                        const float* __restrict__ r2 = v2 + (size_t)i * DIM;
                        float d1 = 0.f, d2 = 0.f;
                        #pragma unroll
                        for (int k4 = 0; k4 < 16; ++k4) {
                            float4 b2 = c2r[k4];
                            d1 += r1[k4*4+0] * b2.x + r1[k4*4+1] * b2.y
                                + r1[k4*4+2] * b2.z + r1[k4*4+3] * b2.w;
                            float4 b1 = c1r[k4];
                            d2 += r2[k4*4+0] * b1.x + r2[k4*4+1] * b1.y
                                + r2[k4*4+2] * b1.z + r2[k4*4+3] * b1.w;
                        }
                        float a    = d1 - d2;
                        float adjv = tanhf(3.0f * a);
                        bool  sat  = (adjv == 1.0f);      // fp32 tanh saturation
                        unsigned long long mask = __ballot(sat);
                        int rank = (int)__popcll(mask & ((1ull << l) - 1ull));
                        if (sat && (cnt[rr] + rank) < KSEL)
                            colbuf[wrow][cnt[rr] + rank] = cbase + h * 64 + l;
                        cnt[rr] += (int)__popcll(mask);
                    }
                }
            }
            #pragma unroll
            for (int rr = 0; rr < 4; ++rr)
                if (cnt[rr] < KSEL) all_done = false;
            if (all_done) { done = true; if (l == 0) wdone[w] = 1; }
        }
        __syncthreads();
        if (wdone[0] && wdone[1] && wdone[2] && wdone[3]) break;  // uniform
    }

    #pragma unroll
    for (int rr = 0; rr < 4; ++rr) {
        const int wrow = w * 4 + rr;
        const int i = rowbase + wrow;
        if (cnt[rr] >= KSEL) {
            if (l < KSEL) {
                int col = colbuf[wrow][l];       // ascending by construction
                size_t o = (size_t)i * KSEL + l;
                out_rows[o] = (float)i;
                out_cols[o] = (float)col;
                out_data[o] = 1.0f;              // saturated value, exact
            }
        } else if (l == 0) {
            // exact serial fallback: top-32 by (value desc, index asc), then col-sort.
            float bv[KSEL]; int bc[KSEL];
            #pragma unroll
            for (int k = 0; k < KSEL; ++k) { bv[k] = -1.0f; bc[k] = 0; }
            for (int j = 0; j < N; ++j) {
                float d1 = 0.f, d2 = 0.f;
                for (int k = 0; k < DIM; ++k) {
                    d1 += v1[(size_t)i * DIM + k] * v2[(size_t)j * DIM + k];
                    d2 += v2[(size_t)i * DIM + k] * v1[(size_t)j * DIM + k];
                }
                float adjv = fmaxf(tanhf(3.0f * (d1 - d2)), 0.0f);
                if (adjv > bv[KSEL - 1]) {       // strict: earlier equal index wins
                    int p = KSEL - 1;
                    while (p > 0 && bv[p - 1] < adjv) {
                        bv[p] = bv[p - 1]; bc[p] = bc[p - 1]; --p;
                    }
                    bv[p] = adjv; bc[p] = j;
                }
            }
            for (int x = 1; x < KSEL; ++x) {     // sort by column ascending
                float tv = bv[x]; int tc = bc[x]; int y = x - 1;
                while (y >= 0 && bc[y] > tc) { bv[y+1] = bv[y]; bc[y+1] = bc[y]; --y; }
                bv[y + 1] = tv; bc[y + 1] = tc;
            }
            for (int k = 0; k < KSEL; ++k) {
                size_t o = (size_t)i * KSEL + k;
                out_rows[o] = (float)i;
                out_cols[o] = (float)bc[k];
                out_data[o] = bv[k];
            }
        }
    }
}

// ---------------------------------------------------------------------------
extern "C" void kernel_launch(void* const* d_in, const int* in_sizes, int n_in,
                              void* d_out, int out_size, void* d_ws, size_t ws_size,
                              hipStream_t stream) {
    const int*   idx  = (const int*)  d_in[0];
    const float* emb1 = (const float*)d_in[1];
    const float* emb2 = (const float*)d_in[2];
    const float* w1   = (const float*)d_in[3];
    const float* b1   = (const float*)d_in[4];
    // d_in[5], d_in[6] = lin2_w / lin2_b -- unused by the reference (faithful).

    float* v1 = (float*)d_ws;                  // [N][DIM] fp32
    float* v2 = v1 + (size_t)N * DIM;          // [N][DIM] fp32  (4 MB total)

    float* out      = (float*)d_out;           // [2*N*K index | N*K data], all fp32
    float* out_rows = out;
    float* out_cols = out + (size_t)N * KSEL;
    float* out_data = out + (size_t)2 * N * KSEL;

    embed_linear_tanh<<<2 * N / 32, 256, 0, stream>>>(idx, emb1, emb2, w1, b1, v1, v2);
    build_graph<<<N / 16, 256, 0, stream>>>(v1, v2, out_rows, out_cols, out_data);
}

// Round 4
// 91.909 us; speedup vs baseline: 1.0063x; 1.0063x over previous
//
#include <hip/hip_runtime.h>
#include <math.h>

#define N    8192
#define DIM  64
#define KSEL 32

// ---------------------------------------------------------------------------
// Kernel A v4 (round-2 proven): v = tanh(3 * (emb[idx] @ W^T + b))
// Coalesced staging, 16 rows/block, grid 1024 (4 blocks/CU, 16 waves/CU):
//   - W row l -> 16 float4 VGPRs, pulled ONCE per wave from a [64][68]-padded
//     LDS copy (16 ds_read_b128, 8-way conflict, one-time: irrelevant).
//   - e[r] read as ds_read_b128 BROADCASTS (wave-uniform address, conflict-
//     free) -- 16 LDS instrs/row instead of ~128 b32 reads.
// Inner loop: 64 v_fmac + 16 broadcast b128 per row -> VALU-issue-bound.
// FP accumulation order: sequential k=0..63, tanhf(3*acc) -> v1/v2
// bit-identical to every passing version.
// ---------------------------------------------------------------------------
__global__ __launch_bounds__(256) void embed_linear_tanh(
    const int*   __restrict__ idx,
    const float* __restrict__ emb1,
    const float* __restrict__ emb2,
    const float* __restrict__ W,     // [DIM][DIM], out[d] = dot(e, W[d,:]) + b[d]
    const float* __restrict__ b,
    float* __restrict__ v1,
    float* __restrict__ v2)
{
    __shared__ float Wp[DIM][DIM + 4];   // +4 pad: rows stay 16B-aligned (272 B stride)
    __shared__ float e[16][DIM];         // broadcast reads (same addr per wave) -> no pad

    const int t = threadIdx.x;
    const int m = blockIdx.x & 1;                 // 0: emb1->v1, 1: emb2->v2
    const int rowbase = (int)(blockIdx.x >> 1) * 16;
    const float* __restrict__ emb  = m ? emb2 : emb1;
    float*       __restrict__ vout = m ? v2   : v1;

    // stage W (4096 floats) coalesced: 256 threads * 4 float4
    {
        const float4* W4 = (const float4*)W;
        #pragma unroll
        for (int s = 0; s < 4; ++s) {
            int e4 = t + s * 256;          // 0..1023
            float4 wvv = W4[e4];
            int d = e4 >> 4;
            int k = (e4 & 15) * 4;
            *(float4*)&Wp[d][k] = wvv;
        }
    }
    // stage 16 gathered emb rows (1024 floats): thread t -> row t>>4, float4 seg t&15
    {
        int r = t >> 4, seg = t & 15;
        int g = idx[rowbase + r];
        float4 x = ((const float4*)(emb + (size_t)g * DIM))[seg];
        *(float4*)&e[r][seg * 4] = x;
    }
    __syncthreads();

    const int l  = t & 63;   // lane = output dim
    const int wv = t >> 6;   // wave index

    // pull W row l into registers (one-time; 8-way LDS conflict acceptable)
    float4 w[16];
    #pragma unroll
    for (int q = 0; q < 16; ++q) w[q] = *(const float4*)&Wp[l][q * 4];
    const float bias = b[l];

    #pragma unroll
    for (int rr = 0; rr < 4; ++rr) {
        const int r = wv + rr * 4;         // same r across a wave -> e[] broadcast
        float acc = bias;
        #pragma unroll
        for (int q = 0; q < 16; ++q) {
            const float4 ev = *(const float4*)&e[r][q * 4];   // broadcast b128
            acc += ev.x * w[q].x;    // sequential fmac chain: identical FP
            acc += ev.y * w[q].y;    // order to the passing kernel
            acc += ev.z * w[q].z;
            acc += ev.w * w[q].w;
        }
        vout[(size_t)(rowbase + r) * DIM + l] = tanhf(3.0f * acc);
    }
}

// ---------------------------------------------------------------------------
// Kernel B v4 (round-0/2 proven, byte-identical): 64-column chunks,
// cooperative LDS staging (coalesced), per-wave column pull as conflict-free
// b128, scalar-path (s_load) row vectors, ballot-based saturated-column
// collection, early block exit when all 16 rows have 32 columns.
// ---------------------------------------------------------------------------
__global__ __launch_bounds__(256, 2) void build_graph(
    const float* __restrict__ v1,
    const float* __restrict__ v2,
    float* __restrict__ out_rows,
    float* __restrict__ out_cols,
    float* __restrict__ out_data)
{
    __shared__ float4 c1v[16][64];   // [k4][col] : lane l -> start bank 4l%32, conflict-free
    __shared__ float4 c2v[16][64];
    __shared__ int    colbuf[16][KSEL];
    __shared__ int    wdone[4];

    const int t = threadIdx.x;
    const int l = t & 63;            // lane
    const int w = __builtin_amdgcn_readfirstlane(t >> 6);   // wave 0..3, forced SGPR
    const int rowbase = (int)blockIdx.x * 16;

    if (l == 0) wdone[w] = 0;
    __syncthreads();

    int  cnt[4] = {0, 0, 0, 0};      // per-row saturated-count (wave-uniform)
    bool done = false;
    const int sr = t >> 2;           // staging: column row 0..63
    const int sq = t & 3;            // staging: 64B segment within row

    for (int cc = 0; cc < N / 64; ++cc) {
        const int jbase = cc * 64;
        // ---- cooperative staging: 64 column rows of v1,v2 -> LDS ----
        {
            const float4* p1 = (const float4*)(v1 + (size_t)(jbase + sr) * DIM) + sq * 4;
            const float4* p2 = (const float4*)(v2 + (size_t)(jbase + sr) * DIM) + sq * 4;
            #pragma unroll
            for (int s = 0; s < 4; ++s) {
                c1v[sq * 4 + s][sr] = p1[s];
                c2v[sq * 4 + s][sr] = p2[s];
            }
        }
        __syncthreads();

        if (!done) {
            // pull column (jbase+l) into registers: 32 conflict-free b128
            float4 c1r[16], c2r[16];
            #pragma unroll
            for (int k4 = 0; k4 < 16; ++k4) { c1r[k4] = c1v[k4][l]; c2r[k4] = c2v[k4][l]; }

            bool all_done = true;
            #pragma unroll
            for (int rr = 0; rr < 4; ++rr) {
                if (cnt[rr] < KSEL) {                 // wave-uniform branch
                    const int wrow = w * 4 + rr;
                    const int i = rowbase + wrow;                 // uniform
                    const float* __restrict__ r1 = v1 + (size_t)i * DIM;  // uniform -> s_load
                    const float* __restrict__ r2 = v2 + (size_t)i * DIM;
                    float d1 = 0.f, d2 = 0.f;
                    #pragma unroll
                    for (int k4 = 0; k4 < 16; ++k4) {
                        float4 b2 = c2r[k4];
                        d1 += r1[k4*4+0] * b2.x + r1[k4*4+1] * b2.y
                            + r1[k4*4+2] * b2.z + r1[k4*4+3] * b2.w;
                        float4 b1 = c1r[k4];
                        d2 += r2[k4*4+0] * b1.x + r2[k4*4+1] * b1.y
                            + r2[k4*4+2] * b1.z + r2[k4*4+3] * b1.w;
                    }
                    float a    = d1 - d2;
                    float adjv = tanhf(3.0f * a);
                    bool  sat  = (adjv == 1.0f);      // fp32 tanh saturation
                    unsigned long long mask = __ballot(sat);
                    int rank = (int)__popcll(mask & ((1ull << l) - 1ull));
                    if (sat && (cnt[rr] + rank) < KSEL) colbuf[wrow][cnt[rr] + rank] = jbase + l;
                    cnt[rr] += (int)__popcll(mask);
                    if (cnt[rr] < KSEL) all_done = false;
                }
            }
            if (all_done) { done = true; if (l == 0) wdone[w] = 1; }
        }
        __syncthreads();
        if (wdone[0] && wdone[1] && wdone[2] && wdone[3]) break;  // uniform
    }

    #pragma unroll
    for (int rr = 0; rr < 4; ++rr) {
        const int wrow = w * 4 + rr;
        const int i = rowbase + wrow;
        if (cnt[rr] >= KSEL) {
            if (l < KSEL) {
                int col = colbuf[wrow][l];       // ascending by construction
                size_t o = (size_t)i * KSEL + l;
                out_rows[o] = (float)i;
                out_cols[o] = (float)col;
                out_data[o] = 1.0f;              // saturated value, exact
            }
        } else if (l == 0) {
            // exact serial fallback: top-32 by (value desc, index asc), then col-sort.
            float bv[KSEL]; int bc[KSEL];
            #pragma unroll
            for (int k = 0; k < KSEL; ++k) { bv[k] = -1.0f; bc[k] = 0; }
            for (int j = 0; j < N; ++j) {
                float d1 = 0.f, d2 = 0.f;
                for (int k = 0; k < DIM; ++k) {
                    d1 += v1[(size_t)i * DIM + k] * v2[(size_t)j * DIM + k];
                    d2 += v2[(size_t)i * DIM + k] * v1[(size_t)j * DIM + k];
                }
                float adjv = fmaxf(tanhf(3.0f * (d1 - d2)), 0.0f);
                if (adjv > bv[KSEL - 1]) {       // strict: earlier equal index wins
                    int p = KSEL - 1;
                    while (p > 0 && bv[p - 1] < adjv) {
                        bv[p] = bv[p - 1]; bc[p] = bc[p - 1]; --p;
                    }
                    bv[p] = adjv; bc[p] = j;
                }
            }
            for (int x = 1; x < KSEL; ++x) {     // sort by column ascending
                float tv = bv[x]; int tc = bc[x]; int y = x - 1;
                while (y >= 0 && bc[y] > tc) { bv[y+1] = bv[y]; bc[y+1] = bc[y]; --y; }
                bv[y + 1] = tv; bc[y + 1] = tc;
            }
            for (int k = 0; k < KSEL; ++k) {
                size_t o = (size_t)i * KSEL + k;
                out_rows[o] = (float)i;
                out_cols[o] = (float)bc[k];
                out_data[o] = bv[k];
            }
        }
    }
}

// ---------------------------------------------------------------------------
extern "C" void kernel_launch(void* const* d_in, const int* in_sizes, int n_in,
                              void* d_out, int out_size, void* d_ws, size_t ws_size,
                              hipStream_t stream) {
    const int*   idx  = (const int*)  d_in[0];
    const float* emb1 = (const float*)d_in[1];
    const float* emb2 = (const float*)d_in[2];
    const float* w1   = (const float*)d_in[3];
    const float* b1   = (const float*)d_in[4];
    // d_in[5], d_in[6] = lin2_w / lin2_b -- unused by the reference (faithful).

    float* v1 = (float*)d_ws;                  // [N][DIM] fp32
    float* v2 = v1 + (size_t)N * DIM;          // [N][DIM] fp32  (4 MB total)

    float* out      = (float*)d_out;           // [2*N*K index | N*K data], all fp32
    float* out_rows = out;
    float* out_cols = out + (size_t)N * KSEL;
    float* out_data = out + (size_t)2 * N * KSEL;

    embed_linear_tanh<<<2 * N / 16, 256, 0, stream>>>(idx, emb1, emb2, w1, b1, v1, v2);
    build_graph<<<N / 16, 256, 0, stream>>>(v1, v2, out_rows, out_cols, out_data);
}